// Round 10
// baseline (6046.044 us; speedup 1.0000x reference)
//
#include <hip/hip_runtime.h>
#include <cstdint>
#include <cstddef>

// Problem constants (B=8, N=2048, M=256)
#define NB 8
#define NN 2048
#define MM 256

typedef unsigned long long u64;

// monotone float->uint map; canonicalize -0 to +0 so float ties == key ties
__device__ __forceinline__ unsigned mapf(float f) {
  unsigned u = __float_as_uint(f + 0.f);
  return ((int)u >= 0) ? (u ^ 0x80000000u) : ~u;
}
__device__ __forceinline__ u64 shflx_u64(u64 v, int m) {
  unsigned lo = (unsigned)__shfl_xor((int)(unsigned)v, m);
  unsigned hi = (unsigned)__shfl_xor((int)(v >> 32), m);
  return ((u64)hi << 32) | lo;
}
__device__ __forceinline__ u64 agent_load(const u64* p) {
  return __hip_atomic_load(p, __ATOMIC_RELAXED, __HIP_MEMORY_SCOPE_AGENT);
}

// ---------------------------------------------------------------------------
// Phase A: LSTM trajectory — TWO interleaved batch-chains per block, with
// issue-early / check-late polling (T14 applied to the exchange).
//
// grid(4,8) x 1024 thr. Block (p,q) runs batches {2p, 2p+1} ("chains"),
// q-slice [32q,32q+32), alternating phases A,B,A,B... Weights wreg and xb
// are BATCH-INDEPENDENT (dec/w_ih/w_hh/biases shared) — only c, hbuf, and
// Pbuf regions are per-chain, so interleaving costs ~0 registers.
//
// Per phase (chain ch, iteration tt):
//   BAR A
//   wave 1: ISSUE the 4 poll loads for the OTHER chain (tag ot) -> regs.
//           The compiler's vmcnt(0)-before-barrier drains them at BAR B,
//           overlapping the ~700cy probe RT with the matvec (round 9 paid
//           this RT serially in a dedicated poll section).
//   all:    matvec chain ch from hbuf[ch] (c8-rotated conflict-free reads),
//           c8-butterfly, activation -> act
//   BAR B
//   wave 0 (lanes<32): cell update chain ch; DENSE 32-lane publish tag tt+1
//           (round-8 law: scattered publishes dirty 64B sectors); own-slice
//           shortcut into hbuf[ch]; Hall trajectory store.
//   wave 1: CHECK pre-issued tags (exact match; data was published ~1 full
//           phase ago by remotes -> usually first-probe hit; miss = spin
//           reload, round-9 semantics); write hbuf[other] non-own words.
// Each chain's publish->visibility latency hides under the other chain's
// compute phase. Equilibrium step = 2 x max(compute, residual-sync).
//
// Exchange medium/laws unchanged (survivors of rounds 0-9): LLC relaxed
// agent atomics, PACKED tagged u64 (padding = 13x fetch amplification),
// parity double-buffer, Pbuf zeroed at launch (tag 0 never awaited).
// Overwrite/progress induction: a remote can write tag ot+2 into the slot
// we pre-loaded only after OUR publish of ot+1 for that chain — which is
// program-ordered AFTER our check of ot. Tag-miss only ever means "not yet
// published": spin reload. No circular wait (phase-A deps are only on
// remote phase-A tails of the previous iteration; same for B).
// hbuf writes all occur post-BAR-B and are consumed after the next BAR A;
// act is written between BAR A/BAR B and consumed post-BAR-B of the same
// phase; next phase's act writes wait on BAR A which requires wave 0 (tail
// reader) — no races.
// ---------------------------------------------------------------------------
__global__ __launch_bounds__(1024) void lstm_kernel(
    const float* __restrict__ z_g, const float* __restrict__ dec,
    const float* __restrict__ h0, const float* __restrict__ w_ih,
    const float* __restrict__ w_hh, const float* __restrict__ b_ih,
    const float* __restrict__ b_hh, float* __restrict__ Hall,
    u64* __restrict__ Pbuf)
{
  const int p = blockIdx.x;        // batch pair 0..3
  const int q = blockIdx.y;
  const int tid = threadIdx.x;
  const int w = tid >> 6;
  const int lane = tid & 63;
  const int rr = lane >> 3;        // row within wave 0..7
  const int c8 = lane & 7;         // col segment 0..7
  const int lr = 8 * w + rr;       // local gate row 0..127
  const int g = lr >> 5;           // gate 0..3 (i,f,g,o) — wave-uniform
  const int m = lr & 31;
  const int grow = g * 256 + 32 * q + m;

  __shared__ __align__(16) float hbuf[2][256];   // per-chain h
  __shared__ __align__(16) float act[128];       // shared (phase-local)

  // recurrent weights, pre-rotated by c8 (conflict-free matvec reads);
  // BATCH-INDEPENDENT -> shared by both chains
  float wreg[32];
  {
    const float* wr = w_hh + (size_t)grow * MM + 32 * c8;
    #pragma unroll
    for (int jj = 0; jj < 8; ++jj) {
      float4 v = *(const float4*)(wr + 4 * ((jj + c8) & 7));
      wreg[4 * jj + 0] = v.x; wreg[4 * jj + 1] = v.y;
      wreg[4 * jj + 2] = v.z; wreg[4 * jj + 3] = v.w;
    }
  }

  // xb = (dec @ w_ih.T)[grow] + b_ih[grow] + b_hh[grow] — batch-independent
  float xb;
  {
    const float* wr = w_ih + (size_t)grow * MM + 32 * c8;
    float pc = 0.f;
    #pragma unroll
    for (int i = 0; i < 8; ++i) {
      float4 wv = *(const float4*)(wr + 4 * i);
      float4 dv = *(const float4*)(dec + 32 * c8 + 4 * i);
      pc += wv.x * dv.x + wv.y * dv.y + wv.z * dv.z + wv.w * dv.w;
    }
    pc += __shfl_xor(pc, 1); pc += __shfl_xor(pc, 2); pc += __shfl_xor(pc, 4);
    xb = pc + b_ih[grow] + b_hh[grow];
  }

  float cmy[2] = {0.f, 0.f};       // per-chain cell state (static-indexed)
  if (tid < 32) {
    cmy[0] = z_g[(2 * p + 0) * MM + 32 * q + tid];
    cmy[1] = z_g[(2 * p + 1) * MM + 32 * q + tid];
  }
  if (tid < 256) { hbuf[0][tid] = h0[tid]; hbuf[1][tid] = h0[tid]; }

  u64* Pb0 = Pbuf + (size_t)(2 * p + 0) * 512;
  u64* Pb1 = Pbuf + (size_t)(2 * p + 1) * 512;
  float* Hb0 = Hall + (size_t)(2 * p + 0) * NN * MM + 32 * q;
  float* Hb1 = Hall + (size_t)(2 * p + 1) * NN * MM + 32 * q;

  // own-slice membership of the 4 polled strides (per-lane constants)
  const bool own0 = ((lane >> 5) + 0) == q;   // word lane
  const bool own1 = ((lane >> 5) + 2) == q;   // word 64+lane
  const bool own2 = ((lane >> 5) + 4) == q;   // word 128+lane
  const bool own3 = ((lane >> 5) + 6) == q;   // word 192+lane

  for (int tt = 0; tt < NN; ++tt) {
    #pragma unroll
    for (int ch = 0; ch < 2; ++ch) {
      // phase ch consumes chain ch tag tt; pre-services the OTHER chain:
      //   ch==0 -> other = 1, ot = tt   (consumed this iteration, phase 1)
      //   ch==1 -> other = 0, ot = tt+1 (consumed next iteration, phase 0)
      const int och = 1 - ch;
      const int ot = tt + ch;
      const bool otv = (ot >= 1) && (ot < NN);
      u64* Pbo = (ch == 0) ? Pb1 : Pb0;

      __syncthreads();                               // BAR A

      // ---- wave 1: ISSUE other-chain poll loads (drain lands at BAR B) --
      u64 a0 = 0, a1 = 0, a2 = 0, a3 = 0;
      const u64* pa = Pbo + ((ot & 1) << 8);
      if (w == 1 && otv) {
        a0 = agent_load(pa + lane);
        a1 = agent_load(pa + 64 + lane);
        a2 = agent_load(pa + 128 + lane);
        a3 = agent_load(pa + 192 + lane);
      }

      // ---- matvec chain ch (rotated, conflict-free LDS reads) ----
      const float4* h4 = (const float4*)hbuf[ch];
      float s0 = 0.f, s1 = 0.f, s2 = 0.f, s3 = 0.f;
      #pragma unroll
      for (int jj = 0; jj < 8; ++jj) {
        float4 hv = h4[8 * c8 + ((jj + c8) & 7)];
        s0 = fmaf(hv.x, wreg[4 * jj + 0], s0);
        s1 = fmaf(hv.y, wreg[4 * jj + 1], s1);
        s2 = fmaf(hv.z, wreg[4 * jj + 2], s2);
        s3 = fmaf(hv.w, wreg[4 * jj + 3], s3);
      }
      float s = (s0 + s1) + (s2 + s3);
      s += __shfl_xor(s, 1); s += __shfl_xor(s, 2); s += __shfl_xor(s, 4);
      const float gsum = s + xb;

      // activation (wave-uniform branch: g = w>>2)
      float a;
      if ((w >> 2) == 2) { const float e = __expf(-2.f * gsum); a = 2.f / (1.f + e) - 1.f; }
      else               { a = 1.f / (1.f + __expf(-gsum)); }
      if (c8 == 0) act[lr] = a;
      __syncthreads();                               // BAR B

      // ---- wave 0: cell update + dense publish chain ch ----
      if (tid < 32) {
        const float i_g = act[tid], f_g = act[32 + tid];
        const float g_g = act[64 + tid], o_g = act[96 + tid];
        float c = cmy[ch];
        c = f_g * c + i_g * g_g;
        cmy[ch] = c;
        const float e2 = __expf(-2.f * c);
        const float hn = o_g * (2.f / (1.f + e2) - 1.f);
        const u64 pk = ((u64)(unsigned)(tt + 1) << 32) | (u64)__float_as_uint(hn);
        u64* Pbc = (ch == 0) ? Pb0 : Pb1;
        float* Hbc = (ch == 0) ? Hb0 : Hb1;
        __hip_atomic_store(Pbc + (((tt + 1) & 1) << 8) + 32 * q + tid, pk,
                           __ATOMIC_RELAXED, __HIP_MEMORY_SCOPE_AGENT);
        hbuf[ch][32 * q + tid] = hn;        // own-slice shortcut
        Hbc[(size_t)tt * MM + tid] = hn;    // trajectory for the Q gemm
      }

      // ---- wave 1: CHECK pre-issued tags, write hbuf[och] (write-late) --
      if (w == 1 && otv) {
        const unsigned tg = (unsigned)ot;
        for (;;) {
          const bool ok = (own0 | ((unsigned)(a0 >> 32) == tg))
                        & (own1 | ((unsigned)(a1 >> 32) == tg))
                        & (own2 | ((unsigned)(a2 >> 32) == tg))
                        & (own3 | ((unsigned)(a3 >> 32) == tg));
          if (__all((int)ok)) break;
          a0 = agent_load(pa + lane);
          a1 = agent_load(pa + 64 + lane);
          a2 = agent_load(pa + 128 + lane);
          a3 = agent_load(pa + 192 + lane);
        }
        if (!own0) hbuf[och][lane]       = __uint_as_float((unsigned)a0);
        if (!own1) hbuf[och][64 + lane]  = __uint_as_float((unsigned)a1);
        if (!own2) hbuf[och][128 + lane] = __uint_as_float((unsigned)a2);
        if (!own3) hbuf[och][192 + lane] = __uint_as_float((unsigned)a3);
      }
      // hbuf[och] readers start after the next BAR A (wave 1 must arrive).
    }
  }
}

// ---------------------------------------------------------------------------
// C = A @ B^T (+ col bias). 128x128 tile, 256 threads, 8x8 micro-tile.
// ---------------------------------------------------------------------------
__global__ __launch_bounds__(256) void gemm128(
    const float* __restrict__ A, const float* __restrict__ B,
    float* __restrict__ C, const float* __restrict__ bias,
    int K, int Ncol, long sA, long sB, long sC)
{
  __shared__ __align__(16) float As[32][132];
  __shared__ __align__(16) float Bs[32][132];
  const int tid = threadIdx.x;
  const int tx = tid & 15;
  const int ty = tid >> 4;
  const int row0 = blockIdx.y * 128;
  const int col0 = blockIdx.x * 128;
  const float* Ab = A + (size_t)blockIdx.z * (size_t)sA;
  const float* Bb = B + (size_t)blockIdx.z * (size_t)sB;
  float* Cb = C + (size_t)blockIdx.z * (size_t)sC;

  float acc[8][8];
  #pragma unroll
  for (int i = 0; i < 8; ++i)
    #pragma unroll
    for (int jj = 0; jj < 8; ++jj) acc[i][jj] = 0.f;

  for (int k0 = 0; k0 < K; k0 += 32) {
    #pragma unroll
    for (int it = 0; it < 4; ++it) {
      const int idx = tid + it * 256;
      const int r = idx >> 3;
      const int c4 = (idx & 7) << 2;
      float4 va = *(const float4*)(Ab + (size_t)(row0 + r) * K + k0 + c4);
      float4 vb = *(const float4*)(Bb + (size_t)(col0 + r) * K + k0 + c4);
      As[c4 + 0][r] = va.x; As[c4 + 1][r] = va.y;
      As[c4 + 2][r] = va.z; As[c4 + 3][r] = va.w;
      Bs[c4 + 0][r] = vb.x; Bs[c4 + 1][r] = vb.y;
      Bs[c4 + 2][r] = vb.z; Bs[c4 + 3][r] = vb.w;
    }
    __syncthreads();
    #pragma unroll
    for (int kk = 0; kk < 32; ++kk) {
      float4 a0 = *(const float4*)&As[kk][ty * 4];
      float4 a1 = *(const float4*)&As[kk][64 + ty * 4];
      float4 b0 = *(const float4*)&Bs[kk][tx * 4];
      float4 b1 = *(const float4*)&Bs[kk][64 + tx * 4];
      const float av[8] = {a0.x, a0.y, a0.z, a0.w, a1.x, a1.y, a1.z, a1.w};
      const float bv[8] = {b0.x, b0.y, b0.z, b0.w, b1.x, b1.y, b1.z, b1.w};
      #pragma unroll
      for (int i = 0; i < 8; ++i)
        #pragma unroll
        for (int jj = 0; jj < 8; ++jj)
          acc[i][jj] = fmaf(av[i], bv[jj], acc[i][jj]);
    }
    __syncthreads();
  }

  #pragma unroll
  for (int i = 0; i < 8; ++i) {
    const int r = row0 + ((i < 4) ? (ty * 4 + i) : (64 + ty * 4 + i - 4));
    float* cp = Cb + (size_t)r * Ncol + col0;
    float4 o0, o1;
    float* o0p = &o0.x; float* o1p = &o1.x;
    #pragma unroll
    for (int jj = 0; jj < 4; ++jj) {
      float v0 = acc[i][jj], v1 = acc[i][jj + 4];
      if (bias) {
        v0 += bias[col0 + tx * 4 + jj];
        v1 += bias[col0 + 64 + tx * 4 + jj];
      }
      o0p[jj] = v0; o1p[jj] = v1;
    }
    *(float4*)(cp + tx * 4) = o0;
    *(float4*)(cp + 64 + tx * 4) = o1;
  }
}

// ---------------------------------------------------------------------------
// Phase D: exact greedy masked argmax chain, one block (512 thr) per batch.
// ---------------------------------------------------------------------------
__global__ __launch_bounds__(512) void select_block(
    const float* __restrict__ S, int* __restrict__ sel)
{
  const int b = blockIdx.x;
  const int tid = threadIdx.x;
  const int w = tid >> 6;          // 0..7
  const int lane = tid & 63;
  const float* Sb = S + (size_t)b * NN * NN + 4 * tid;
  int* selb = sel + b * NN;

  __shared__ u64 partial[2][8];

  for (int i = tid; i < NN; i += 512) selb[i] = 0x7fffffff;
  __syncthreads();

  unsigned mybits = 0;                 // used flags for my 4 columns
  const unsigned base = 2047u - 4u * (unsigned)tid;

  auto stepf = [&](float4 v, int t) {
    u64 k0 = (mybits & 1u) ? 0 : (((u64)mapf(v.x) << 32) | (base - 0u));
    u64 k1 = (mybits & 2u) ? 0 : (((u64)mapf(v.y) << 32) | (base - 1u));
    u64 k2 = (mybits & 4u) ? 0 : (((u64)mapf(v.z) << 32) | (base - 2u));
    u64 k3 = (mybits & 8u) ? 0 : (((u64)mapf(v.w) << 32) | (base - 3u));
    u64 k = k0 > k1 ? k0 : k1;
    if (k2 > k) k = k2;
    if (k3 > k) k = k3;
    #pragma unroll
    for (int off = 1; off < 64; off <<= 1) {
      u64 o = shflx_u64(k, off);
      if (o > k) k = o;
    }
    if (lane == 0) partial[t & 1][w] = k;
    __syncthreads();
    u64 pk = partial[t & 1][lane & 7];
    #pragma unroll
    for (int off = 1; off < 8; off <<= 1) {
      u64 o = shflx_u64(pk, off);
      if (o > pk) pk = o;
    }
    const int idx = 2047 - (int)(pk & 0x7ff);
    if ((idx >> 2) == tid) mybits |= 1u << (idx & 3);
    if (tid == 0) selb[idx] = t;
  };

  float4 r0 = *(const float4*)(Sb + (size_t)0 * NN);
  float4 r1 = *(const float4*)(Sb + (size_t)1 * NN);
  float4 r2 = *(const float4*)(Sb + (size_t)2 * NN);
  float4 r3 = *(const float4*)(Sb + (size_t)3 * NN);
  for (int t = 0; t < NN; t += 4) {
    const size_t p4 = (size_t)((t + 4 < NN) ? t + 4 : NN - 1) * NN;
    const size_t p5 = (size_t)((t + 5 < NN) ? t + 5 : NN - 1) * NN;
    const size_t p6 = (size_t)((t + 6 < NN) ? t + 6 : NN - 1) * NN;
    const size_t p7 = (size_t)((t + 7 < NN) ? t + 7 : NN - 1) * NN;
    stepf(r0, t);     r0 = *(const float4*)(Sb + p4);
    stepf(r1, t + 1); r1 = *(const float4*)(Sb + p5);
    stepf(r2, t + 2); r2 = *(const float4*)(Sb + p6);
    stepf(r3, t + 3); r3 = *(const float4*)(Sb + p7);
  }
}

// ---------------------------------------------------------------------------
// Phase E: in-place masked softmax per row. Row t masks n iff sel[n] < t.
// ---------------------------------------------------------------------------
__global__ __launch_bounds__(256) void softmax_kernel(
    float* __restrict__ out, const int* __restrict__ sel)
{
  const int t = blockIdx.x;
  const int b = blockIdx.y;
  const int tid = threadIdx.x;
  float* row = out + ((size_t)b * NN + t) * NN;
  const int* selb = sel + b * NN;
  __shared__ float red[8];

  float v[8];
  int sl[8];
  #pragma unroll
  for (int u = 0; u < 2; ++u) {
    float4 f = *(const float4*)(row + u * 1024 + tid * 4);
    int4 s4 = *(const int4*)(selb + u * 1024 + tid * 4);
    v[u * 4 + 0] = f.x; v[u * 4 + 1] = f.y; v[u * 4 + 2] = f.z; v[u * 4 + 3] = f.w;
    sl[u * 4 + 0] = s4.x; sl[u * 4 + 1] = s4.y; sl[u * 4 + 2] = s4.z; sl[u * 4 + 3] = s4.w;
  }

  float mx = -3.0e38f;
  #pragma unroll
  for (int e = 0; e < 8; ++e)
    if (sl[e] >= t) mx = fmaxf(mx, v[e]);
  #pragma unroll
  for (int off = 1; off < 64; off <<= 1) mx = fmaxf(mx, __shfl_xor(mx, off));
  if ((tid & 63) == 0) red[tid >> 6] = mx;
  __syncthreads();
  mx = fmaxf(fmaxf(red[0], red[1]), fmaxf(red[2], red[3]));

  float e8[8];
  float sum = 0.f;
  #pragma unroll
  for (int e = 0; e < 8; ++e) {
    float ex = (sl[e] >= t) ? __expf(v[e] - mx) : 0.f;
    e8[e] = ex;
    sum += ex;
  }
  #pragma unroll
  for (int off = 1; off < 64; off <<= 1) sum += __shfl_xor(sum, off);
  if ((tid & 63) == 0) red[4 + (tid >> 6)] = sum;
  __syncthreads();
  sum = red[4] + red[5] + red[6] + red[7];
  const float inv = 1.f / sum;

  #pragma unroll
  for (int u = 0; u < 2; ++u) {
    float4 o;
    o.x = e8[u * 4 + 0] * inv; o.y = e8[u * 4 + 1] * inv;
    o.z = e8[u * 4 + 2] * inv; o.w = e8[u * 4 + 3] * inv;
    *(float4*)(row + u * 1024 + tid * 4) = o;
  }
}

// ---------------------------------------------------------------------------
// ws layout (floats): keys[4194304] | Q[4194304] | Pbuf(u64 4096 = 32KB,
//                     PACKED) | sel[16384]   ~ 33.7 MB
// Hall (h trajectory, [B][NN][256] f32 = 16.8MB) borrows d_out (134MB),
// consumed by the Q gemm before gemm2 overwrites it.
// ---------------------------------------------------------------------------
extern "C" void kernel_launch(void* const* d_in, const int* in_sizes, int n_in,
                              void* d_out, int out_size, void* d_ws, size_t ws_size,
                              hipStream_t stream)
{
  (void)in_sizes; (void)n_in; (void)out_size; (void)ws_size;
  const float* emb  = (const float*)d_in[0];
  const float* z_g  = (const float*)d_in[1];
  const float* dec  = (const float*)d_in[2];
  const float* h0   = (const float*)d_in[3];
  const float* w_ih = (const float*)d_in[4];
  const float* w_hh = (const float*)d_in[5];
  const float* b_ih = (const float*)d_in[6];
  const float* b_hh = (const float*)d_in[7];
  const float* Wq   = (const float*)d_in[8];
  const float* bq   = (const float*)d_in[9];
  const float* Wk   = (const float*)d_in[10];
  const float* bk   = (const float*)d_in[11];
  float* out = (float*)d_out;
  float* ws  = (float*)d_ws;

  float* keys  = ws;
  float* Q     = ws + 4194304;
  u64*   Pbuf  = (u64*)(ws + 8388608);    // 4096 u64 = 32 KB (packed)
  int*   sel   = (int*)(ws + 8396800);
  float* Hall  = out;                     // borrowed until the Q gemm

  // zero exchange tags (tag 0 never awaited; awaited tags >= 1)
  hipMemsetAsync(Pbuf, 0, 4096 * sizeof(u64), stream);

  lstm_kernel<<<dim3(4, 8), 1024, 0, stream>>>(
      z_g, dec, h0, w_ih, w_hh, b_ih, b_hh, Hall, Pbuf);

  // Q = Hall @ Wq.T + bq  ([16384,256] x [256,256]^T)
  gemm128<<<dim3(MM / 128, (NB * NN) / 128, 1), 256, 0, stream>>>(
      Hall, Wq, Q, bq, MM, MM, 0, 0, 0);

  // keys = emb @ Wk.T + bk
  gemm128<<<dim3(MM / 128, (NB * NN) / 128, 1), 256, 0, stream>>>(
      emb, Wk, keys, bk, MM, MM, 0, 0, 0);

  // S[b] = Q[b] @ keys[b].T -> d_out (overwrites Hall, already consumed)
  gemm128<<<dim3(NN / 128, NN / 128, NB), 256, 0, stream>>>(
      Q, keys, out, nullptr, MM, NN,
      (long)NN * MM, (long)NN * MM, (long)NN * NN);

  select_block<<<NB, 512, 0, stream>>>(out, sel);

  softmax_kernel<<<dim3(NN, NB), 256, 0, stream>>>(out, sel);
}

// Round 11
// 5283.472 us; speedup vs baseline: 1.1443x; 1.1443x over previous
//
#include <hip/hip_runtime.h>
#include <cstdint>
#include <cstddef>

// Problem constants (B=8, N=2048, M=256)
#define NB 8
#define NN 2048
#define MM 256

typedef unsigned long long u64;

// monotone float->uint map; canonicalize -0 to +0 so float ties == key ties
__device__ __forceinline__ unsigned mapf(float f) {
  unsigned u = __float_as_uint(f + 0.f);
  return ((int)u >= 0) ? (u ^ 0x80000000u) : ~u;
}
__device__ __forceinline__ u64 shflx_u64(u64 v, int m) {
  unsigned lo = (unsigned)__shfl_xor((int)(unsigned)v, m);
  unsigned hi = (unsigned)__shfl_xor((int)(v >> 32), m);
  return ((u64)hi << 32) | lo;
}
__device__ __forceinline__ u64 agent_load(const u64* p) {
  return __hip_atomic_load(p, __ATOMIC_RELAXED, __HIP_MEMORY_SCOPE_AGENT);
}

// ---------------------------------------------------------------------------
// Phase A: LSTM trajectory — round-9 structure with PRODUCER/POLLER WAVE
// SPLIT.
//
// Round-9 (2746us verified) had wave 0 both publish (agent store) and poll
// (agent loads). vmcnt counts outstanding STORES too: the s_waitcnt before
// the first tag check therefore drained the publish's LLC ack (~700cy) on
// the critical path every step. Fix: wave 0 POLLS ONLY (its vmcnt holds
// only poll loads; own-slice words are skipped, so it never depends on our
// store); wave 1 runs the tail (cell update + dense 32-lane publish + Hall
// + own-slice hbuf shortcut). The two run CONCURRENTLY after BAR B.
//
// Deadlock/overwrite (same induction as rounds 5-9): wave 1 never waits on
// global data; publishing tag tt+1 requires the block passed poll(tt),
// which requires all remote blocks past their tag-(tt-1) consumption — the
// slot being overwritten is dead. Pbuf zeroed at launch (tag 0 never
// awaited). hbuf writes (wave-1 tail, pre-BAR-A) are ordered against
// matvec reads by BAR A.
//
// Exchange laws (survivors of rounds 0-10): LLC relaxed agent atomics;
// PACKED words (padding = 13x fetch amplification); dense single-store
// publish (scattered stores dirty 64B sectors); single-wave single-phase
// poll at ~1 probe/RT (deeper pipelining or more pollers regress);
// interleaving chains per block cannot help (batches already parallel).
// ---------------------------------------------------------------------------
__global__ __launch_bounds__(1024) void lstm_kernel(
    const float* __restrict__ z_g, const float* __restrict__ dec,
    const float* __restrict__ h0, const float* __restrict__ w_ih,
    const float* __restrict__ w_hh, const float* __restrict__ b_ih,
    const float* __restrict__ b_hh, float* __restrict__ Hall,
    u64* __restrict__ Pbuf)
{
  const int b = blockIdx.x;
  const int q = blockIdx.y;
  const int tid = threadIdx.x;
  const int w = tid >> 6;
  const int lane = tid & 63;
  const int rr = lane >> 3;        // row within wave 0..7
  const int c8 = lane & 7;         // col segment 0..7
  const int lr = 8 * w + rr;       // local gate row 0..127
  const int g = lr >> 5;           // gate 0..3 (i,f,g,o) — wave-uniform
  const int m = lr & 31;
  const int grow = g * 256 + 32 * q + m;

  __shared__ __align__(16) float hbuf[256];
  __shared__ __align__(16) float act[128];

  // recurrent weights, pre-rotated by c8 so the matvec LDS reads are
  // conflict-free: wreg slot jj holds cols 32*c8 + 4*((jj+c8)&7) ..+3
  float wreg[32];
  {
    const float* wr = w_hh + (size_t)grow * MM + 32 * c8;
    #pragma unroll
    for (int jj = 0; jj < 8; ++jj) {
      float4 v = *(const float4*)(wr + 4 * ((jj + c8) & 7));
      wreg[4 * jj + 0] = v.x; wreg[4 * jj + 1] = v.y;
      wreg[4 * jj + 2] = v.z; wreg[4 * jj + 3] = v.w;
    }
  }

  // xb = (dec @ w_ih.T)[grow] + b_ih[grow] + b_hh[grow] (c8-butterfly)
  float xb;
  {
    const float* wr = w_ih + (size_t)grow * MM + 32 * c8;
    float p = 0.f;
    #pragma unroll
    for (int i = 0; i < 8; ++i) {
      float4 wv = *(const float4*)(wr + 4 * i);
      float4 dv = *(const float4*)(dec + 32 * c8 + 4 * i);
      p += wv.x * dv.x + wv.y * dv.y + wv.z * dv.z + wv.w * dv.w;
    }
    p += __shfl_xor(p, 1); p += __shfl_xor(p, 2); p += __shfl_xor(p, 4);
    xb = p + b_ih[grow] + b_hh[grow];
  }

  // cell state lives on WAVE 1 lanes <32 (the producer wave)
  float c_my = 0.f;
  if (w == 1 && lane < 32) c_my = z_g[b * MM + 32 * q + lane];
  if (tid < 256) hbuf[tid] = h0[tid];

  u64* Pb = Pbuf + (size_t)b * 512;
  float* Hb = Hall + (size_t)b * NN * MM + 32 * q;

  // own-slice membership of the 4 polled strides (per-lane constants)
  const bool own0 = ((lane >> 5) + 0) == q;   // word lane
  const bool own1 = ((lane >> 5) + 2) == q;   // word 64+lane
  const bool own2 = ((lane >> 5) + 4) == q;   // word 128+lane
  const bool own3 = ((lane >> 5) + 6) == q;   // word 192+lane

  for (int tt = 0; tt < NN; ++tt) {
    // ---- poll h^(tt): wave 0 ONLY (no stores in its vmcnt queue) ----
    if (tt > 0 && w == 0) {
      const u64* pa = Pb + ((tt & 1) << 8);
      const unsigned tg = (unsigned)tt;
      u64 a0, a1, a2, a3;
      for (;;) {
        a0 = agent_load(pa + lane);
        a1 = agent_load(pa + 64 + lane);
        a2 = agent_load(pa + 128 + lane);
        a3 = agent_load(pa + 192 + lane);
        const bool ok = (own0 | ((unsigned)(a0 >> 32) == tg))
                      & (own1 | ((unsigned)(a1 >> 32) == tg))
                      & (own2 | ((unsigned)(a2 >> 32) == tg))
                      & (own3 | ((unsigned)(a3 >> 32) == tg));
        if (__all((int)ok)) break;
      }
      // own-slice words were written to hbuf by wave 1's tail (same bits)
      if (!own0) hbuf[lane]       = __uint_as_float((unsigned)a0);
      if (!own1) hbuf[64 + lane]  = __uint_as_float((unsigned)a1);
      if (!own2) hbuf[128 + lane] = __uint_as_float((unsigned)a2);
      if (!own3) hbuf[192 + lane] = __uint_as_float((unsigned)a3);
    }
    __syncthreads();                                  // BAR A

    // ---- matvec over this lane's 32-col segment (rotated, no conflicts) --
    const float4* h4 = (const float4*)hbuf;
    float a0 = 0.f, a1 = 0.f, a2 = 0.f, a3 = 0.f;
    #pragma unroll
    for (int jj = 0; jj < 8; ++jj) {
      float4 hv = h4[8 * c8 + ((jj + c8) & 7)];
      a0 = fmaf(hv.x, wreg[4 * jj + 0], a0);
      a1 = fmaf(hv.y, wreg[4 * jj + 1], a1);
      a2 = fmaf(hv.z, wreg[4 * jj + 2], a2);
      a3 = fmaf(hv.w, wreg[4 * jj + 3], a3);
    }
    float s = (a0 + a1) + (a2 + a3);
    s += __shfl_xor(s, 1); s += __shfl_xor(s, 2); s += __shfl_xor(s, 4);
    const float gsum = s + xb;

    // activation (wave-uniform branch: g = w>>2)
    float a;
    if ((w >> 2) == 2) { const float e = __expf(-2.f * gsum); a = 2.f / (1.f + e) - 1.f; }
    else               { a = 1.f / (1.f + __expf(-gsum)); }
    if (c8 == 0) act[lr] = a;
    __syncthreads();                                  // BAR B

    // ---- WAVE 1 tail: cell update + dense publish (concurrent with wave
    //      0's next poll — our store never enters the poller's vmcnt) ----
    if (w == 1 && lane < 32) {
      const float i_g = act[lane], f_g = act[32 + lane];
      const float g_g = act[64 + lane], o_g = act[96 + lane];
      c_my = f_g * c_my + i_g * g_g;
      const float e2 = __expf(-2.f * c_my);
      const float hn = o_g * (2.f / (1.f + e2) - 1.f);
      const u64 pk = ((u64)(unsigned)(tt + 1) << 32) | (u64)__float_as_uint(hn);
      __hip_atomic_store(Pb + (((tt + 1) & 1) << 8) + 32 * q + lane, pk,
                         __ATOMIC_RELAXED, __HIP_MEMORY_SCOPE_AGENT);
      hbuf[32 * q + lane] = hn;           // own-slice shortcut for the poll
      Hb[(size_t)tt * MM + lane] = hn;    // trajectory for the Q gemm
    }
    // no barrier: hbuf writes (wave 1 tail / wave 0 poll) are pre-BAR-A of
    // the next iteration; matvec reads follow BAR A.
  }
}

// ---------------------------------------------------------------------------
// C = A @ B^T (+ col bias). 128x128 tile, 256 threads, 8x8 micro-tile.
// ---------------------------------------------------------------------------
__global__ __launch_bounds__(256) void gemm128(
    const float* __restrict__ A, const float* __restrict__ B,
    float* __restrict__ C, const float* __restrict__ bias,
    int K, int Ncol, long sA, long sB, long sC)
{
  __shared__ __align__(16) float As[32][132];
  __shared__ __align__(16) float Bs[32][132];
  const int tid = threadIdx.x;
  const int tx = tid & 15;
  const int ty = tid >> 4;
  const int row0 = blockIdx.y * 128;
  const int col0 = blockIdx.x * 128;
  const float* Ab = A + (size_t)blockIdx.z * (size_t)sA;
  const float* Bb = B + (size_t)blockIdx.z * (size_t)sB;
  float* Cb = C + (size_t)blockIdx.z * (size_t)sC;

  float acc[8][8];
  #pragma unroll
  for (int i = 0; i < 8; ++i)
    #pragma unroll
    for (int jj = 0; jj < 8; ++jj) acc[i][jj] = 0.f;

  for (int k0 = 0; k0 < K; k0 += 32) {
    #pragma unroll
    for (int it = 0; it < 4; ++it) {
      const int idx = tid + it * 256;
      const int r = idx >> 3;
      const int c4 = (idx & 7) << 2;
      float4 va = *(const float4*)(Ab + (size_t)(row0 + r) * K + k0 + c4);
      float4 vb = *(const float4*)(Bb + (size_t)(col0 + r) * K + k0 + c4);
      As[c4 + 0][r] = va.x; As[c4 + 1][r] = va.y;
      As[c4 + 2][r] = va.z; As[c4 + 3][r] = va.w;
      Bs[c4 + 0][r] = vb.x; Bs[c4 + 1][r] = vb.y;
      Bs[c4 + 2][r] = vb.z; Bs[c4 + 3][r] = vb.w;
    }
    __syncthreads();
    #pragma unroll
    for (int kk = 0; kk < 32; ++kk) {
      float4 a0 = *(const float4*)&As[kk][ty * 4];
      float4 a1 = *(const float4*)&As[kk][64 + ty * 4];
      float4 b0 = *(const float4*)&Bs[kk][tx * 4];
      float4 b1 = *(const float4*)&Bs[kk][64 + tx * 4];
      const float av[8] = {a0.x, a0.y, a0.z, a0.w, a1.x, a1.y, a1.z, a1.w};
      const float bv[8] = {b0.x, b0.y, b0.z, b0.w, b1.x, b1.y, b1.z, b1.w};
      #pragma unroll
      for (int i = 0; i < 8; ++i)
        #pragma unroll
        for (int jj = 0; jj < 8; ++jj)
          acc[i][jj] = fmaf(av[i], bv[jj], acc[i][jj]);
    }
    __syncthreads();
  }

  #pragma unroll
  for (int i = 0; i < 8; ++i) {
    const int r = row0 + ((i < 4) ? (ty * 4 + i) : (64 + ty * 4 + i - 4));
    float* cp = Cb + (size_t)r * Ncol + col0;
    float4 o0, o1;
    float* o0p = &o0.x; float* o1p = &o1.x;
    #pragma unroll
    for (int jj = 0; jj < 4; ++jj) {
      float v0 = acc[i][jj], v1 = acc[i][jj + 4];
      if (bias) {
        v0 += bias[col0 + tx * 4 + jj];
        v1 += bias[col0 + 64 + tx * 4 + jj];
      }
      o0p[jj] = v0; o1p[jj] = v1;
    }
    *(float4*)(cp + tx * 4) = o0;
    *(float4*)(cp + 64 + tx * 4) = o1;
  }
}

// ---------------------------------------------------------------------------
// Phase D: exact greedy masked argmax chain, one block (512 thr) per batch.
// PAIRWISE TOP-2 SPECULATION: rows (t, t+1) reduced concurrently; row t+1
// keeps top-2 so its result resolves exactly after sel_t is known:
//   sel_{t+1} = (col(top1) != sel_t) ? top1 : top2
// Exact: keys are unique per column (value<<32 | index-code), and the only
// mask delta between the two rows is the removal of sel_t's column. Halves
// the barrier count and overlaps the two shuffle-reduce chains.
// ---------------------------------------------------------------------------
__global__ __launch_bounds__(512) void select_block(
    const float* __restrict__ S, int* __restrict__ sel)
{
  const int b = blockIdx.x;
  const int tid = threadIdx.x;
  const int w = tid >> 6;          // 0..7
  const int lane = tid & 63;
  const float* Sb = S + (size_t)b * NN * NN + 4 * tid;
  int* selb = sel + b * NN;

  __shared__ u64 pA[2][8], pB1[2][8], pB2[2][8];

  for (int i = tid; i < NN; i += 512) selb[i] = 0x7fffffff;
  __syncthreads();

  unsigned mybits = 0;                 // used flags for my 4 columns
  const unsigned base = 2047u - 4u * (unsigned)tid;

  auto keys4 = [&](float4 v, u64* k) {
    k[0] = (mybits & 1u) ? 0 : (((u64)mapf(v.x) << 32) | (base - 0u));
    k[1] = (mybits & 2u) ? 0 : (((u64)mapf(v.y) << 32) | (base - 1u));
    k[2] = (mybits & 4u) ? 0 : (((u64)mapf(v.z) << 32) | (base - 2u));
    k[3] = (mybits & 8u) ? 0 : (((u64)mapf(v.w) << 32) | (base - 3u));
  };

  // process rows (t, t+1) together
  auto pairf = [&](float4 vA, float4 vB, int t) {
    const int buf = (t >> 1) & 1;
    u64 ka[4], kb[4];
    keys4(vA, ka);
    keys4(vB, kb);

    // row A: local top-1
    u64 A = ka[0] > ka[1] ? ka[0] : ka[1];
    if (ka[2] > A) A = ka[2];
    if (ka[3] > A) A = ka[3];

    // row B: local top-2 of 4
    u64 m01 = kb[0] > kb[1] ? kb[0] : kb[1];
    u64 n01 = kb[0] > kb[1] ? kb[1] : kb[0];
    u64 m23 = kb[2] > kb[3] ? kb[2] : kb[3];
    u64 n23 = kb[2] > kb[3] ? kb[3] : kb[2];
    u64 B1, B2;
    if (m01 > m23) { B1 = m01; B2 = (m23 > n01) ? m23 : n01; }
    else           { B1 = m23; B2 = (m01 > n23) ? m01 : n23; }

    // interleaved wave butterflies (A: top-1, B: top-2)
    #pragma unroll
    for (int off = 1; off < 64; off <<= 1) {
      u64 oA = shflx_u64(A, off);
      u64 o1 = shflx_u64(B1, off);
      u64 o2 = shflx_u64(B2, off);
      if (oA > A) A = oA;
      if (o1 > B1) { B2 = (B1 > o2) ? B1 : o2; B1 = o1; }
      else if (o1 > B2) { B2 = o1; }
    }
    if (lane == 0) { pA[buf][w] = A; pB1[buf][w] = B1; pB2[buf][w] = B2; }
    __syncthreads();
    u64 FA = pA[buf][lane & 7];
    u64 C1 = pB1[buf][lane & 7];
    u64 C2 = pB2[buf][lane & 7];
    #pragma unroll
    for (int off = 1; off < 8; off <<= 1) {
      u64 oA = shflx_u64(FA, off);
      u64 o1 = shflx_u64(C1, off);
      u64 o2 = shflx_u64(C2, off);
      if (oA > FA) FA = oA;
      if (o1 > C1) { C2 = (C1 > o2) ? C1 : o2; C1 = o1; }
      else if (o1 > C2) { C2 = o1; }
    }

    const int selA = 2047 - (int)(FA & 0x7ffu);
    const u64 chosen = ((C1 & 0x7ffu) != (FA & 0x7ffu)) ? C1 : C2;
    const int selB = 2047 - (int)(chosen & 0x7ffu);
    if ((selA >> 2) == tid) mybits |= 1u << (selA & 3);
    if ((selB >> 2) == tid) mybits |= 1u << (selB & 3);
    if (tid == 0) { selb[selA] = t; selb[selB] = t + 1; }
  };

  float4 r0 = *(const float4*)(Sb + (size_t)0 * NN);
  float4 r1 = *(const float4*)(Sb + (size_t)1 * NN);
  float4 r2 = *(const float4*)(Sb + (size_t)2 * NN);
  float4 r3 = *(const float4*)(Sb + (size_t)3 * NN);
  for (int t = 0; t < NN; t += 4) {
    const size_t p4 = (size_t)((t + 4 < NN) ? t + 4 : NN - 1) * NN;
    const size_t p5 = (size_t)((t + 5 < NN) ? t + 5 : NN - 1) * NN;
    const size_t p6 = (size_t)((t + 6 < NN) ? t + 6 : NN - 1) * NN;
    const size_t p7 = (size_t)((t + 7 < NN) ? t + 7 : NN - 1) * NN;
    pairf(r0, r1, t);     r0 = *(const float4*)(Sb + p4);
    r1 = *(const float4*)(Sb + p5);
    pairf(r2, r3, t + 2); r2 = *(const float4*)(Sb + p6);
    r3 = *(const float4*)(Sb + p7);
  }
}

// ---------------------------------------------------------------------------
// Phase E: in-place masked softmax per row. Row t masks n iff sel[n] < t.
// ---------------------------------------------------------------------------
__global__ __launch_bounds__(256) void softmax_kernel(
    float* __restrict__ out, const int* __restrict__ sel)
{
  const int t = blockIdx.x;
  const int b = blockIdx.y;
  const int tid = threadIdx.x;
  float* row = out + ((size_t)b * NN + t) * NN;
  const int* selb = sel + b * NN;
  __shared__ float red[8];

  float v[8];
  int sl[8];
  #pragma unroll
  for (int u = 0; u < 2; ++u) {
    float4 f = *(const float4*)(row + u * 1024 + tid * 4);
    int4 s4 = *(const int4*)(selb + u * 1024 + tid * 4);
    v[u * 4 + 0] = f.x; v[u * 4 + 1] = f.y; v[u * 4 + 2] = f.z; v[u * 4 + 3] = f.w;
    sl[u * 4 + 0] = s4.x; sl[u * 4 + 1] = s4.y; sl[u * 4 + 2] = s4.z; sl[u * 4 + 3] = s4.w;
  }

  float mx = -3.0e38f;
  #pragma unroll
  for (int e = 0; e < 8; ++e)
    if (sl[e] >= t) mx = fmaxf(mx, v[e]);
  #pragma unroll
  for (int off = 1; off < 64; off <<= 1) mx = fmaxf(mx, __shfl_xor(mx, off));
  if ((tid & 63) == 0) red[tid >> 6] = mx;
  __syncthreads();
  mx = fmaxf(fmaxf(red[0], red[1]), fmaxf(red[2], red[3]));

  float e8[8];
  float sum = 0.f;
  #pragma unroll
  for (int e = 0; e < 8; ++e) {
    float ex = (sl[e] >= t) ? __expf(v[e] - mx) : 0.f;
    e8[e] = ex;
    sum += ex;
  }
  #pragma unroll
  for (int off = 1; off < 64; off <<= 1) sum += __shfl_xor(sum, off);
  if ((tid & 63) == 0) red[4 + (tid >> 6)] = sum;
  __syncthreads();
  sum = red[4] + red[5] + red[6] + red[7];
  const float inv = 1.f / sum;

  #pragma unroll
  for (int u = 0; u < 2; ++u) {
    float4 o;
    o.x = e8[u * 4 + 0] * inv; o.y = e8[u * 4 + 1] * inv;
    o.z = e8[u * 4 + 2] * inv; o.w = e8[u * 4 + 3] * inv;
    *(float4*)(row + u * 1024 + tid * 4) = o;
  }
}

// ---------------------------------------------------------------------------
// ws layout (floats): keys[4194304] | Q[4194304] | Pbuf(u64 4096 = 32KB,
//                     PACKED) | sel[16384]   ~ 33.7 MB
// Hall (h trajectory, [B][NN][256] f32 = 16.8MB) borrows d_out (134MB),
// consumed by the Q gemm before gemm2 overwrites it.
// ---------------------------------------------------------------------------
extern "C" void kernel_launch(void* const* d_in, const int* in_sizes, int n_in,
                              void* d_out, int out_size, void* d_ws, size_t ws_size,
                              hipStream_t stream)
{
  (void)in_sizes; (void)n_in; (void)out_size; (void)ws_size;
  const float* emb  = (const float*)d_in[0];
  const float* z_g  = (const float*)d_in[1];
  const float* dec  = (const float*)d_in[2];
  const float* h0   = (const float*)d_in[3];
  const float* w_ih = (const float*)d_in[4];
  const float* w_hh = (const float*)d_in[5];
  const float* b_ih = (const float*)d_in[6];
  const float* b_hh = (const float*)d_in[7];
  const float* Wq   = (const float*)d_in[8];
  const float* bq   = (const float*)d_in[9];
  const float* Wk   = (const float*)d_in[10];
  const float* bk   = (const float*)d_in[11];
  float* out = (float*)d_out;
  float* ws  = (float*)d_ws;

  float* keys  = ws;
  float* Q     = ws + 4194304;
  u64*   Pbuf  = (u64*)(ws + 8388608);    // 4096 u64 = 32 KB (packed)
  int*   sel   = (int*)(ws + 8396800);
  float* Hall  = out;                     // borrowed until the Q gemm

  // zero exchange tags (tag 0 never awaited; awaited tags >= 1)
  hipMemsetAsync(Pbuf, 0, 4096 * sizeof(u64), stream);

  lstm_kernel<<<dim3(NB, 8), 1024, 0, stream>>>(
      z_g, dec, h0, w_ih, w_hh, b_ih, b_hh, Hall, Pbuf);

  // Q = Hall @ Wq.T + bq  ([16384,256] x [256,256]^T)
  gemm128<<<dim3(MM / 128, (NB * NN) / 128, 1), 256, 0, stream>>>(
      Hall, Wq, Q, bq, MM, MM, 0, 0, 0);

  // keys = emb @ Wk.T + bk
  gemm128<<<dim3(MM / 128, (NB * NN) / 128, 1), 256, 0, stream>>>(
      emb, Wk, keys, bk, MM, MM, 0, 0, 0);

  // S[b] = Q[b] @ keys[b].T -> d_out (overwrites Hall, already consumed)
  gemm128<<<dim3(NN / 128, NN / 128, NB), 256, 0, stream>>>(
      Q, keys, out, nullptr, MM, NN,
      (long)NN * MM, (long)NN * MM, (long)NN * NN);

  select_block<<<NB, 512, 0, stream>>>(out, sel);

  softmax_kernel<<<dim3(NN, NB), 256, 0, stream>>>(out, sel);
}

// Round 12
// 4647.768 us; speedup vs baseline: 1.3008x; 1.1368x over previous
//
#include <hip/hip_runtime.h>
#include <cstdint>
#include <cstddef>

// Problem constants (B=8, N=2048, M=256)
#define NB 8
#define NN 2048
#define MM 256

typedef unsigned long long u64;

// monotone float->uint map; canonicalize -0 to +0 so float ties == key ties
__device__ __forceinline__ unsigned mapf(float f) {
  unsigned u = __float_as_uint(f + 0.f);
  return ((int)u >= 0) ? (u ^ 0x80000000u) : ~u;
}
__device__ __forceinline__ u64 shflx_u64(u64 v, int m) {
  unsigned lo = (unsigned)__shfl_xor((int)(unsigned)v, m);
  unsigned hi = (unsigned)__shfl_xor((int)(v >> 32), m);
  return ((u64)hi << 32) | lo;
}
__device__ __forceinline__ u64 agent_load(const u64* p) {
  return __hip_atomic_load(p, __ATOMIC_RELAXED, __HIP_MEMORY_SCOPE_AGENT);
}

// ---------------------------------------------------------------------------
// Phase A: LSTM trajectory — round-11 form (best verified: 2694us).
// Producer/poller wave split: wave 0 polls only (no stores in its vmcnt
// queue); wave 1 runs the tail (cell update + dense publish + Hall).
//
// Exchange laws (survivors of rounds 0-11): LLC relaxed agent atomics;
// PACKED words (padding = 13x fetch amplification); dense single-store
// publish (scattered stores dirty 64B sectors; WRITE arithmetic confirms
// agent stores write through to HBM 1:1); single-wave single-phase poll at
// ~1 probe/RT (deeper pipelining, more pollers, chain interleave all
// regress). Remaining step time ~3160cy = compute ~700 + store visibility
// + discovery overshoot — the inter-XCD LLC round-trip floor for this
// exchange granularity.
// ---------------------------------------------------------------------------
__global__ __launch_bounds__(1024) void lstm_kernel(
    const float* __restrict__ z_g, const float* __restrict__ dec,
    const float* __restrict__ h0, const float* __restrict__ w_ih,
    const float* __restrict__ w_hh, const float* __restrict__ b_ih,
    const float* __restrict__ b_hh, float* __restrict__ Hall,
    u64* __restrict__ Pbuf)
{
  const int b = blockIdx.x;
  const int q = blockIdx.y;
  const int tid = threadIdx.x;
  const int w = tid >> 6;
  const int lane = tid & 63;
  const int rr = lane >> 3;        // row within wave 0..7
  const int c8 = lane & 7;         // col segment 0..7
  const int lr = 8 * w + rr;       // local gate row 0..127
  const int g = lr >> 5;           // gate 0..3 (i,f,g,o) — wave-uniform
  const int m = lr & 31;
  const int grow = g * 256 + 32 * q + m;

  __shared__ __align__(16) float hbuf[256];
  __shared__ __align__(16) float act[128];

  // recurrent weights, pre-rotated by c8 so the matvec LDS reads are
  // conflict-free: wreg slot jj holds cols 32*c8 + 4*((jj+c8)&7) ..+3
  float wreg[32];
  {
    const float* wr = w_hh + (size_t)grow * MM + 32 * c8;
    #pragma unroll
    for (int jj = 0; jj < 8; ++jj) {
      float4 v = *(const float4*)(wr + 4 * ((jj + c8) & 7));
      wreg[4 * jj + 0] = v.x; wreg[4 * jj + 1] = v.y;
      wreg[4 * jj + 2] = v.z; wreg[4 * jj + 3] = v.w;
    }
  }

  // xb = (dec @ w_ih.T)[grow] + b_ih[grow] + b_hh[grow] (c8-butterfly)
  float xb;
  {
    const float* wr = w_ih + (size_t)grow * MM + 32 * c8;
    float p = 0.f;
    #pragma unroll
    for (int i = 0; i < 8; ++i) {
      float4 wv = *(const float4*)(wr + 4 * i);
      float4 dv = *(const float4*)(dec + 32 * c8 + 4 * i);
      p += wv.x * dv.x + wv.y * dv.y + wv.z * dv.z + wv.w * dv.w;
    }
    p += __shfl_xor(p, 1); p += __shfl_xor(p, 2); p += __shfl_xor(p, 4);
    xb = p + b_ih[grow] + b_hh[grow];
  }

  // cell state lives on WAVE 1 lanes <32 (the producer wave)
  float c_my = 0.f;
  if (w == 1 && lane < 32) c_my = z_g[b * MM + 32 * q + lane];
  if (tid < 256) hbuf[tid] = h0[tid];

  u64* Pb = Pbuf + (size_t)b * 512;
  float* Hb = Hall + (size_t)b * NN * MM + 32 * q;

  // own-slice membership of the 4 polled strides (per-lane constants)
  const bool own0 = ((lane >> 5) + 0) == q;   // word lane
  const bool own1 = ((lane >> 5) + 2) == q;   // word 64+lane
  const bool own2 = ((lane >> 5) + 4) == q;   // word 128+lane
  const bool own3 = ((lane >> 5) + 6) == q;   // word 192+lane

  for (int tt = 0; tt < NN; ++tt) {
    // ---- poll h^(tt): wave 0 ONLY (no stores in its vmcnt queue) ----
    if (tt > 0 && w == 0) {
      const u64* pa = Pb + ((tt & 1) << 8);
      const unsigned tg = (unsigned)tt;
      u64 a0, a1, a2, a3;
      for (;;) {
        a0 = agent_load(pa + lane);
        a1 = agent_load(pa + 64 + lane);
        a2 = agent_load(pa + 128 + lane);
        a3 = agent_load(pa + 192 + lane);
        const bool ok = (own0 | ((unsigned)(a0 >> 32) == tg))
                      & (own1 | ((unsigned)(a1 >> 32) == tg))
                      & (own2 | ((unsigned)(a2 >> 32) == tg))
                      & (own3 | ((unsigned)(a3 >> 32) == tg));
        if (__all((int)ok)) break;
      }
      // own-slice words were written to hbuf by wave 1's tail (same bits)
      if (!own0) hbuf[lane]       = __uint_as_float((unsigned)a0);
      if (!own1) hbuf[64 + lane]  = __uint_as_float((unsigned)a1);
      if (!own2) hbuf[128 + lane] = __uint_as_float((unsigned)a2);
      if (!own3) hbuf[192 + lane] = __uint_as_float((unsigned)a3);
    }
    __syncthreads();                                  // BAR A

    // ---- matvec over this lane's 32-col segment (rotated, no conflicts) --
    const float4* h4 = (const float4*)hbuf;
    float a0 = 0.f, a1 = 0.f, a2 = 0.f, a3 = 0.f;
    #pragma unroll
    for (int jj = 0; jj < 8; ++jj) {
      float4 hv = h4[8 * c8 + ((jj + c8) & 7)];
      a0 = fmaf(hv.x, wreg[4 * jj + 0], a0);
      a1 = fmaf(hv.y, wreg[4 * jj + 1], a1);
      a2 = fmaf(hv.z, wreg[4 * jj + 2], a2);
      a3 = fmaf(hv.w, wreg[4 * jj + 3], a3);
    }
    float s = (a0 + a1) + (a2 + a3);
    s += __shfl_xor(s, 1); s += __shfl_xor(s, 2); s += __shfl_xor(s, 4);
    const float gsum = s + xb;

    // activation (wave-uniform branch: g = w>>2)
    float a;
    if ((w >> 2) == 2) { const float e = __expf(-2.f * gsum); a = 2.f / (1.f + e) - 1.f; }
    else               { a = 1.f / (1.f + __expf(-gsum)); }
    if (c8 == 0) act[lr] = a;
    __syncthreads();                                  // BAR B

    // ---- WAVE 1 tail: cell update + dense publish (concurrent with wave
    //      0's next poll — our store never enters the poller's vmcnt) ----
    if (w == 1 && lane < 32) {
      const float i_g = act[lane], f_g = act[32 + lane];
      const float g_g = act[64 + lane], o_g = act[96 + lane];
      c_my = f_g * c_my + i_g * g_g;
      const float e2 = __expf(-2.f * c_my);
      const float hn = o_g * (2.f / (1.f + e2) - 1.f);
      const u64 pk = ((u64)(unsigned)(tt + 1) << 32) | (u64)__float_as_uint(hn);
      __hip_atomic_store(Pb + (((tt + 1) & 1) << 8) + 32 * q + lane, pk,
                         __ATOMIC_RELAXED, __HIP_MEMORY_SCOPE_AGENT);
      hbuf[32 * q + lane] = hn;           // own-slice shortcut for the poll
      Hb[(size_t)tt * MM + lane] = hn;    // trajectory for the Q gemm
    }
    // no barrier: hbuf writes (wave 1 tail / wave 0 poll) are pre-BAR-A of
    // the next iteration; matvec reads follow BAR A.
  }
}

// ---------------------------------------------------------------------------
// C = A @ B^T (+ col bias). 128x128 tile, 256 threads, 8x8 micro-tile.
// ---------------------------------------------------------------------------
__global__ __launch_bounds__(256) void gemm128(
    const float* __restrict__ A, const float* __restrict__ B,
    float* __restrict__ C, const float* __restrict__ bias,
    int K, int Ncol, long sA, long sB, long sC)
{
  __shared__ __align__(16) float As[32][132];
  __shared__ __align__(16) float Bs[32][132];
  const int tid = threadIdx.x;
  const int tx = tid & 15;
  const int ty = tid >> 4;
  const int row0 = blockIdx.y * 128;
  const int col0 = blockIdx.x * 128;
  const float* Ab = A + (size_t)blockIdx.z * (size_t)sA;
  const float* Bb = B + (size_t)blockIdx.z * (size_t)sB;
  float* Cb = C + (size_t)blockIdx.z * (size_t)sC;

  float acc[8][8];
  #pragma unroll
  for (int i = 0; i < 8; ++i)
    #pragma unroll
    for (int jj = 0; jj < 8; ++jj) acc[i][jj] = 0.f;

  for (int k0 = 0; k0 < K; k0 += 32) {
    #pragma unroll
    for (int it = 0; it < 4; ++it) {
      const int idx = tid + it * 256;
      const int r = idx >> 3;
      const int c4 = (idx & 7) << 2;
      float4 va = *(const float4*)(Ab + (size_t)(row0 + r) * K + k0 + c4);
      float4 vb = *(const float4*)(Bb + (size_t)(col0 + r) * K + k0 + c4);
      As[c4 + 0][r] = va.x; As[c4 + 1][r] = va.y;
      As[c4 + 2][r] = va.z; As[c4 + 3][r] = va.w;
      Bs[c4 + 0][r] = vb.x; Bs[c4 + 1][r] = vb.y;
      Bs[c4 + 2][r] = vb.z; Bs[c4 + 3][r] = vb.w;
    }
    __syncthreads();
    #pragma unroll
    for (int kk = 0; kk < 32; ++kk) {
      float4 a0 = *(const float4*)&As[kk][ty * 4];
      float4 a1 = *(const float4*)&As[kk][64 + ty * 4];
      float4 b0 = *(const float4*)&Bs[kk][tx * 4];
      float4 b1 = *(const float4*)&Bs[kk][64 + tx * 4];
      const float av[8] = {a0.x, a0.y, a0.z, a0.w, a1.x, a1.y, a1.z, a1.w};
      const float bv[8] = {b0.x, b0.y, b0.z, b0.w, b1.x, b1.y, b1.z, b1.w};
      #pragma unroll
      for (int i = 0; i < 8; ++i)
        #pragma unroll
        for (int jj = 0; jj < 8; ++jj)
          acc[i][jj] = fmaf(av[i], bv[jj], acc[i][jj]);
    }
    __syncthreads();
  }

  #pragma unroll
  for (int i = 0; i < 8; ++i) {
    const int r = row0 + ((i < 4) ? (ty * 4 + i) : (64 + ty * 4 + i - 4));
    float* cp = Cb + (size_t)r * Ncol + col0;
    float4 o0, o1;
    float* o0p = &o0.x; float* o1p = &o1.x;
    #pragma unroll
    for (int jj = 0; jj < 4; ++jj) {
      float v0 = acc[i][jj], v1 = acc[i][jj + 4];
      if (bias) {
        v0 += bias[col0 + tx * 4 + jj];
        v1 += bias[col0 + 64 + tx * 4 + jj];
      }
      o0p[jj] = v0; o1p[jj] = v1;
    }
    *(float4*)(cp + tx * 4) = o0;
    *(float4*)(cp + 64 + tx * 4) = o1;
  }
}

// ---------------------------------------------------------------------------
// Phase D: exact greedy masked argmax chain, one block (512 thr) per batch.
// (round-9 verified form; round-11's pairwise top-2 speculation tripled the
// reduce critical path and regressed +630us — reverted)
// ---------------------------------------------------------------------------
__global__ __launch_bounds__(512) void select_block(
    const float* __restrict__ S, int* __restrict__ sel)
{
  const int b = blockIdx.x;
  const int tid = threadIdx.x;
  const int w = tid >> 6;          // 0..7
  const int lane = tid & 63;
  const float* Sb = S + (size_t)b * NN * NN + 4 * tid;
  int* selb = sel + b * NN;

  __shared__ u64 partial[2][8];

  for (int i = tid; i < NN; i += 512) selb[i] = 0x7fffffff;
  __syncthreads();

  unsigned mybits = 0;                 // used flags for my 4 columns
  const unsigned base = 2047u - 4u * (unsigned)tid;

  auto stepf = [&](float4 v, int t) {
    u64 k0 = (mybits & 1u) ? 0 : (((u64)mapf(v.x) << 32) | (base - 0u));
    u64 k1 = (mybits & 2u) ? 0 : (((u64)mapf(v.y) << 32) | (base - 1u));
    u64 k2 = (mybits & 4u) ? 0 : (((u64)mapf(v.z) << 32) | (base - 2u));
    u64 k3 = (mybits & 8u) ? 0 : (((u64)mapf(v.w) << 32) | (base - 3u));
    u64 k = k0 > k1 ? k0 : k1;
    if (k2 > k) k = k2;
    if (k3 > k) k = k3;
    #pragma unroll
    for (int off = 1; off < 64; off <<= 1) {
      u64 o = shflx_u64(k, off);
      if (o > k) k = o;
    }
    if (lane == 0) partial[t & 1][w] = k;
    __syncthreads();
    u64 pk = partial[t & 1][lane & 7];
    #pragma unroll
    for (int off = 1; off < 8; off <<= 1) {
      u64 o = shflx_u64(pk, off);
      if (o > pk) pk = o;
    }
    const int idx = 2047 - (int)(pk & 0x7ff);
    if ((idx >> 2) == tid) mybits |= 1u << (idx & 3);
    if (tid == 0) selb[idx] = t;
  };

  float4 r0 = *(const float4*)(Sb + (size_t)0 * NN);
  float4 r1 = *(const float4*)(Sb + (size_t)1 * NN);
  float4 r2 = *(const float4*)(Sb + (size_t)2 * NN);
  float4 r3 = *(const float4*)(Sb + (size_t)3 * NN);
  for (int t = 0; t < NN; t += 4) {
    const size_t p4 = (size_t)((t + 4 < NN) ? t + 4 : NN - 1) * NN;
    const size_t p5 = (size_t)((t + 5 < NN) ? t + 5 : NN - 1) * NN;
    const size_t p6 = (size_t)((t + 6 < NN) ? t + 6 : NN - 1) * NN;
    const size_t p7 = (size_t)((t + 7 < NN) ? t + 7 : NN - 1) * NN;
    stepf(r0, t);     r0 = *(const float4*)(Sb + p4);
    stepf(r1, t + 1); r1 = *(const float4*)(Sb + p5);
    stepf(r2, t + 2); r2 = *(const float4*)(Sb + p6);
    stepf(r3, t + 3); r3 = *(const float4*)(Sb + p7);
  }
}

// ---------------------------------------------------------------------------
// Phase E: in-place masked softmax per row. Row t masks n iff sel[n] < t.
// ---------------------------------------------------------------------------
__global__ __launch_bounds__(256) void softmax_kernel(
    float* __restrict__ out, const int* __restrict__ sel)
{
  const int t = blockIdx.x;
  const int b = blockIdx.y;
  const int tid = threadIdx.x;
  float* row = out + ((size_t)b * NN + t) * NN;
  const int* selb = sel + b * NN;
  __shared__ float red[8];

  float v[8];
  int sl[8];
  #pragma unroll
  for (int u = 0; u < 2; ++u) {
    float4 f = *(const float4*)(row + u * 1024 + tid * 4);
    int4 s4 = *(const int4*)(selb + u * 1024 + tid * 4);
    v[u * 4 + 0] = f.x; v[u * 4 + 1] = f.y; v[u * 4 + 2] = f.z; v[u * 4 + 3] = f.w;
    sl[u * 4 + 0] = s4.x; sl[u * 4 + 1] = s4.y; sl[u * 4 + 2] = s4.z; sl[u * 4 + 3] = s4.w;
  }

  float mx = -3.0e38f;
  #pragma unroll
  for (int e = 0; e < 8; ++e)
    if (sl[e] >= t) mx = fmaxf(mx, v[e]);
  #pragma unroll
  for (int off = 1; off < 64; off <<= 1) mx = fmaxf(mx, __shfl_xor(mx, off));
  if ((tid & 63) == 0) red[tid >> 6] = mx;
  __syncthreads();
  mx = fmaxf(fmaxf(red[0], red[1]), fmaxf(red[2], red[3]));

  float e8[8];
  float sum = 0.f;
  #pragma unroll
  for (int e = 0; e < 8; ++e) {
    float ex = (sl[e] >= t) ? __expf(v[e] - mx) : 0.f;
    e8[e] = ex;
    sum += ex;
  }
  #pragma unroll
  for (int off = 1; off < 64; off <<= 1) sum += __shfl_xor(sum, off);
  if ((tid & 63) == 0) red[4 + (tid >> 6)] = sum;
  __syncthreads();
  sum = red[4] + red[5] + red[6] + red[7];
  const float inv = 1.f / sum;

  #pragma unroll
  for (int u = 0; u < 2; ++u) {
    float4 o;
    o.x = e8[u * 4 + 0] * inv; o.y = e8[u * 4 + 1] * inv;
    o.z = e8[u * 4 + 2] * inv; o.w = e8[u * 4 + 3] * inv;
    *(float4*)(row + u * 1024 + tid * 4) = o;
  }
}

// ---------------------------------------------------------------------------
// ws layout (floats): keys[4194304] | Q[4194304] | Pbuf(u64 4096 = 32KB,
//                     PACKED) | sel[16384]   ~ 33.7 MB
// Hall (h trajectory, [B][NN][256] f32 = 16.8MB) borrows d_out (134MB),
// consumed by the Q gemm before gemm2 overwrites it.
// ---------------------------------------------------------------------------
extern "C" void kernel_launch(void* const* d_in, const int* in_sizes, int n_in,
                              void* d_out, int out_size, void* d_ws, size_t ws_size,
                              hipStream_t stream)
{
  (void)in_sizes; (void)n_in; (void)out_size; (void)ws_size;
  const float* emb  = (const float*)d_in[0];
  const float* z_g  = (const float*)d_in[1];
  const float* dec  = (const float*)d_in[2];
  const float* h0   = (const float*)d_in[3];
  const float* w_ih = (const float*)d_in[4];
  const float* w_hh = (const float*)d_in[5];
  const float* b_ih = (const float*)d_in[6];
  const float* b_hh = (const float*)d_in[7];
  const float* Wq   = (const float*)d_in[8];
  const float* bq   = (const float*)d_in[9];
  const float* Wk   = (const float*)d_in[10];
  const float* bk   = (const float*)d_in[11];
  float* out = (float*)d_out;
  float* ws  = (float*)d_ws;

  float* keys  = ws;
  float* Q     = ws + 4194304;
  u64*   Pbuf  = (u64*)(ws + 8388608);    // 4096 u64 = 32 KB (packed)
  int*   sel   = (int*)(ws + 8396800);
  float* Hall  = out;                     // borrowed until the Q gemm

  // zero exchange tags (tag 0 never awaited; awaited tags >= 1)
  hipMemsetAsync(Pbuf, 0, 4096 * sizeof(u64), stream);

  lstm_kernel<<<dim3(NB, 8), 1024, 0, stream>>>(
      z_g, dec, h0, w_ih, w_hh, b_ih, b_hh, Hall, Pbuf);

  // Q = Hall @ Wq.T + bq  ([16384,256] x [256,256]^T)
  gemm128<<<dim3(MM / 128, (NB * NN) / 128, 1), 256, 0, stream>>>(
      Hall, Wq, Q, bq, MM, MM, 0, 0, 0);

  // keys = emb @ Wk.T + bk
  gemm128<<<dim3(MM / 128, (NB * NN) / 128, 1), 256, 0, stream>>>(
      emb, Wk, keys, bk, MM, MM, 0, 0, 0);

  // S[b] = Q[b] @ keys[b].T -> d_out (overwrites Hall, already consumed)
  gemm128<<<dim3(NN / 128, NN / 128, NB), 256, 0, stream>>>(
      Q, keys, out, nullptr, MM, NN,
      (long)NN * MM, (long)NN * MM, (long)NN * NN);

  select_block<<<NB, 512, 0, stream>>>(out, sel);

  softmax_kernel<<<dim3(NN, NB), 256, 0, stream>>>(out, sel);
}